// Round 18
// baseline (2053.861 us; speedup 1.0000x reference)
//
#include <hip/hip_runtime.h>

#define NSAMP 384
#define NCOMBO 60
#define NROW 23040
#define KDIM 512
#define NCLS 7463
#define NCLSP 7680
#define NTILE_N 30
#define NTILE_M 180
#define NGRP 30
#define O1_NZ 30
#define O1_KZ 512

typedef short s16x8 __attribute__((ext_vector_type(8)));
typedef short s16x4 __attribute__((ext_vector_type(4)));
typedef float f32x4 __attribute__((ext_vector_type(4)));

// ---- module-level scratch (R16-compatible layout; new arrays appended) ----
__device__ unsigned short g_wc_hi[NCLSP * KDIM];
__device__ unsigned short g_wc_lo[NCLSP * KDIM];
__device__ unsigned short g_h_hi[NROW * KDIM];
__device__ unsigned short g_h_lo[NROW * KDIM];          // layout keeper (unused)
__device__ unsigned short g_rawbf[NROW * 256];          // == [NSAMP][15360]
__device__ unsigned short g_wo1bf[512 * 15360];
__device__ float          g_pmax[NTILE_N * NROW];       // layout keeper (unused)
__device__ int            g_pidx[NTILE_N * NROW];       // layout keeper (unused)
__device__ float          g_part[O1_NZ * NSAMP * 512];
__device__ float          g_h_f32[NROW * KDIM];         // refine source
__device__ float          g_q1v[NGRP * NROW];
__device__ int            g_q1i[NGRP * NROW];
__device__ float          g_q2v[NGRP * NROW];
__device__ int            g_q2i[NGRP * NROW];

__device__ __forceinline__ float bf2f(unsigned short u){
  union { unsigned int i; float f; } v; v.i = ((unsigned int)u) << 16; return v.f;
}
__device__ __forceinline__ unsigned short f2bf(float f){
  union { float f; unsigned int i; } v; v.f = f;
  unsigned int u = v.i;
  unsigned int r = (u + 0x7FFFu + ((u >> 16) & 1u)) >> 16;
  return (unsigned short)r;
}
__device__ __forceinline__ void gload16(const void* g, void* l){
  __builtin_amdgcn_global_load_lds((const __attribute__((address_space(1))) void*)g,
                                   (__attribute__((address_space(3))) void*)l, 16, 0, 0);
}
__device__ __forceinline__ void top2_merge(float& v1, int& i1, float& v2, int& i2,
                                           float wv, int wi){
  if (wv > v1 || (wv == v1 && wi < i1)){ v2 = v1; i2 = i1; v1 = wv; i1 = wi; }
  else if (wv > v2 || (wv == v2 && wi < i2)){ v2 = wv; i2 = wi; }
}

// ---------------- K0: wc -> bf16 hi/lo (pad to 7680) AND wo1 -> bf16 --------------
__global__ __launch_bounds__(256) void k_prep(const float* __restrict__ wc,
                                              const float* __restrict__ wo1)
{
  int b = blockIdx.x;
  if (b < 3840){
    int idx = (b * 256 + threadIdx.x) * 4;
    float4 w = {0.f, 0.f, 0.f, 0.f};
    if (idx < NCLS * KDIM) w = *(const float4*)(wc + idx);
    s16x4 hi, lo;
    float wv[4] = {w.x, w.y, w.z, w.w};
    #pragma unroll
    for (int i = 0; i < 4; ++i){
      unsigned short h = f2bf(wv[i]);
      hi[i] = (short)h;
      lo[i] = (short)f2bf(wv[i] - bf2f(h));
    }
    *(s16x4*)(g_wc_hi + idx) = hi;
    *(s16x4*)(g_wc_lo + idx) = lo;
  } else {
    int idx = ((b - 3840) * 256 + threadIdx.x) * 4;   // covers 512*15360 exactly
    float4 w = *(const float4*)(wo1 + idx);
    s16x4 v;
    v[0] = (short)f2bf(w.x); v[1] = (short)f2bf(w.y);
    v[2] = (short)f2bf(w.z); v[3] = (short)f2bf(w.w);
    *(s16x4*)(g_wo1bf + idx) = v;
  }
}

// ---------------- K1: per-combo features -> h bf16 + h f32 + raw bf16 -------------
__global__ __launch_bounds__(256) void k_features(
    const int* __restrict__ x,
    const float* __restrict__ suit_w, const float* __restrict__ suit_b,
    const float* __restrict__ rank_w, const float* __restrict__ rank_b,
    const float* __restrict__ bns_g, const float* __restrict__ bns_b,
    const float* __restrict__ bns_m, const float* __restrict__ bns_v,
    const float* __restrict__ bnr_g, const float* __restrict__ bnr_b,
    const float* __restrict__ bnr_m, const float* __restrict__ bnr_v,
    const float* __restrict__ w1, const float* __restrict__ b1,
    const float* __restrict__ w2, const float* __restrict__ b2)
{
  __shared__ float raw_s[4][256];
  __shared__ float h1_s[4][512];
  __shared__ float w1s[512];
  __shared__ float w2s[1024];
  __shared__ float b1s[32];
  __shared__ float b2s[32];
  const int tid  = threadIdx.x;
  const int lane = tid & 63;
  const int wv   = tid >> 6;
  const int combo = blockIdx.x * 4 + wv;
  const int s = combo / 60;
  const int k = combo % 60;
  const int hp = k / 10, bt = k % 10;
  const int HP0[6]  = {0,0,0,1,1,2}, HP1[6] = {1,2,3,2,3,3};
  const int BT0[10] = {4,4,4,4,4,4,5,5,5,6};
  const int BT1[10] = {5,5,5,6,6,7,6,6,7,7};
  const int BT2[10] = {6,7,8,7,8,8,7,8,8,8};
  int cards[5] = {HP0[hp], HP1[hp], BT0[bt], BT1[bt], BT2[bt]};
  const int* xp = x + s * 18;
  int rk[5], st[5];
  #pragma unroll
  for (int c = 0; c < 5; ++c){ rk[c] = xp[2*cards[c]]; st[c] = xp[2*cards[c] + 1]; }

  // cooperative weight preload (visible after the first __syncthreads below)
  w1s[tid]       = w1[tid];
  w1s[tid + 256] = w1[tid + 256];
  #pragma unroll
  for (int i = 0; i < 4; ++i) w2s[tid + i * 256] = w2[tid + i * 256];
  if (tid < 32){ b1s[tid] = b1[tid]; b2s[tid] = b2[tid]; }

  {
    s16x4 rv;
    #pragma unroll
    for (int i = 0; i < 4; ++i){
      int e = lane * 4 + i;
      int o = e >> 4, l = e & 15;
      float v;
      if (l < 11){
        float a = 0.f;
        #pragma unroll
        for (int c = 0; c < 5; ++c){
          int d = rk[c] - l;
          if (d >= 0 && d < 5) a += rank_w[o*25 + c*5 + d];
        }
        a += rank_b[o];
        float inv = bnr_g[o] / sqrtf(bnr_v[o] + 1e-5f);
        v = a * inv + (bnr_b[o] - bnr_m[o] * inv);
      } else {
        int j = l - 11;
        float a = suit_b[o];
        #pragma unroll
        for (int c = 0; c < 5; ++c) if (st[c] == j) a += suit_w[o*5 + c];
        float inv = bns_g[o] / sqrtf(bns_v[o] + 1e-5f);
        v = a * inv + (bns_b[o] - bns_m[o] * inv);
      }
      v = fmaxf(v, 0.f);
      raw_s[wv][e] = v;
      rv[i] = (short)f2bf(v);
    }
    *(s16x4*)(g_rawbf + (size_t)s * 15360 + k * 256 + lane * 4) = rv;
  }
  __syncthreads();
  #pragma unroll
  for (int i = 0; i < 8; ++i){
    int e = lane + 64 * i;
    int o = e >> 5, j = e & 31;
    float a = b1s[j];
    #pragma unroll
    for (int l = 0; l < 16; ++l) a += raw_s[wv][o*16 + l] * w1s[j*16 + l];
    h1_s[wv][e] = fmaxf(a, 0.f);
  }
  __syncthreads();
  {
    s16x8 hv;
    float hf[8];
    #pragma unroll
    for (int i = 0; i < 8; ++i){
      int e = lane * 8 + i;
      int o = e >> 5, j = e & 31;
      float a = b2s[j];
      #pragma unroll
      for (int l = 0; l < 32; ++l) a += h1_s[wv][o*32 + l] * w2s[j*32 + l];
      a = fmaxf(a, 0.f);
      hv[i] = (short)f2bf(a);
      hf[i] = a;
    }
    *(s16x8*)(g_h_hi + (size_t)combo * 512 + lane * 8) = hv;
    *(float4*)(g_h_f32 + (size_t)combo * 512 + lane * 8)     = *(float4*)&hf[0];
    *(float4*)(g_h_f32 + (size_t)combo * 512 + lane * 8 + 4) = *(float4*)&hf[4];
  }
}

// ---------------- K2: logits GEMM, 2-segment virtual-K (32 tiles) + TOP-2 ---------
// Skeleton = R16's measured-fast kernel. Virtual K = 1024: t -> (kc=(t>>1)*32,
// seg=t&1); seg0 = ah.bh, seg1 = ah.bl  (logit = ah.(bh+bl), dropped al.b term
// ~1e-4 -- covered by margin-refine). A (h_hi) staged twice per kc -> 2nd touch
// L2-hot, preserving the fast regime's address redundancy. Counted vmcnt(3).
__global__ __launch_bounds__(512, 4) void k_logits(const float* __restrict__ bc)
{
  __shared__ unsigned char lds[49152];
  const int tid  = threadIdx.x;
  const int lane = tid & 63;
  const int wv   = tid >> 6;                 // 0..7
  const int wm   = wv >> 2, wn = wv & 3;     // 2M x 4N
  const int blk  = blockIdx.x;               // 5400 = 30 nt x 180 mt, m-fastest
  const int nt   = blk / NTILE_M;
  const int mt   = blk % NTILE_M;
  const int m0 = mt * 128;
  const int n0 = nt * 256;

  f32x4 acc[4][4];
  #pragma unroll
  for (int i = 0; i < 4; ++i)
    #pragma unroll
    for (int j = 0; j < 4; ++j)
      acc[i][j] = (f32x4){0.f, 0.f, 0.f, 0.f};

  const int rS = wv * 16 + (lane >> 2);              // 0..127
  const int cS = (lane & 3) ^ ((lane >> 3) & 3);     // pre-swizzled source chunk
  auto stage = [&](int buf, int t){
    const int p = t >> 1, seg = t & 1;
    const int kc = p * 32;
    const unsigned short* Bs = seg ? g_wc_lo : g_wc_hi;
    const unsigned base = buf * 24576 + wv * 1024;
    gload16(g_h_hi + (size_t)(m0 + rS) * KDIM + kc + cS * 8, lds + base);
    gload16(Bs + (size_t)(n0 + rS) * KDIM + kc + cS * 8, lds + base + 8192);
    gload16(Bs + (size_t)(n0 + 128 + rS) * KDIM + kc + cS * 8, lds + base + 16384);
  };

  stage(0, 0);
  stage(1, 1);
  asm volatile("s_waitcnt vmcnt(3)" ::: "memory");   // tile0's 3 loads done
  __builtin_amdgcn_sched_barrier(0);
  __builtin_amdgcn_s_barrier();
  asm volatile("" ::: "memory");

  const int q = lane >> 4;                   // 16B k-chunk 0..3
  #pragma unroll 1
  for (int t = 0; t < 32; ++t){
    const unsigned cb = (unsigned)(t & 1) * 24576;
    s16x8 af[4], bf[4];
    #pragma unroll
    for (int i = 0; i < 4; ++i){
      int row = wm * 64 + i * 16 + (lane & 15);
      af[i] = *(const s16x8*)(lds + cb + row * 64 + ((q ^ ((row >> 1) & 3)) << 4));
    }
    #pragma unroll
    for (int j = 0; j < 4; ++j){
      int row = wn * 64 + j * 16 + (lane & 15);
      bf[j] = *(const s16x8*)(lds + cb + 8192 + row * 64 + ((q ^ ((row >> 1) & 3)) << 4));
    }
    __builtin_amdgcn_s_setprio(1);
    #pragma unroll
    for (int i = 0; i < 4; ++i)
      #pragma unroll
      for (int j = 0; j < 4; ++j)
        acc[i][j] = __builtin_amdgcn_mfma_f32_16x16x32_bf16(af[i], bf[j], acc[i][j], 0, 0, 0);
    __builtin_amdgcn_s_setprio(0);
    __builtin_amdgcn_sched_barrier(0);
    __builtin_amdgcn_s_barrier();            // all waves done reading buffer cb
    asm volatile("" ::: "memory");
    if (t + 2 < 32){
      stage(t & 1, t + 2);                   // overwrite cb; loads fly across barriers
      asm volatile("s_waitcnt vmcnt(3)" ::: "memory");  // tile t+1 confirmed
    } else {
      asm volatile("s_waitcnt vmcnt(0)" ::: "memory");  // tail drain
    }
    __builtin_amdgcn_sched_barrier(0);
    __builtin_amdgcn_s_barrier();
    asm volatile("" ::: "memory");
  }

  // epilogue: + bc, per-row TOP-2 over this 256-col tile (ties -> lowest index)
  float* cm1 = (float*)lds;                  // [128 rows][4 wn]
  int*   ci1 = (int*)(lds + 2048);
  float* cm2 = (float*)(lds + 4096);
  int*   ci2 = (int*)(lds + 6144);
  const int cc = lane & 15;
  const int qq = lane >> 4;
  #pragma unroll
  for (int i = 0; i < 4; ++i){
    #pragma unroll
    for (int r = 0; r < 4; ++r){
      float v1 = -__builtin_inff(); int i1 = 0x7FFFFFFF;
      float v2 = -__builtin_inff(); int i2 = 0x7FFFFFFF;
      #pragma unroll
      for (int j = 0; j < 4; ++j){
        int col = n0 + wn * 64 + j * 16 + cc;
        if (col < NCLS){
          float v = acc[i][j][r] + bc[col];
          top2_merge(v1, i1, v2, i2, v, col);
        }
      }
      for (int s = 1; s < 16; s <<= 1){
        float ov1 = __shfl_xor(v1, s); int oi1 = __shfl_xor(i1, s);
        float ov2 = __shfl_xor(v2, s); int oi2 = __shfl_xor(i2, s);
        top2_merge(v1, i1, v2, i2, ov1, oi1);
        top2_merge(v1, i1, v2, i2, ov2, oi2);
      }
      if (cc == 0){
        int rloc = wm * 64 + i * 16 + qq * 4 + r;
        cm1[rloc * 4 + wn] = v1; ci1[rloc * 4 + wn] = i1;
        cm2[rloc * 4 + wn] = v2; ci2[rloc * 4 + wn] = i2;
      }
    }
  }
  __syncthreads();
  if (tid < 128){
    float v1 = cm1[tid * 4]; int i1 = ci1[tid * 4];
    float v2 = cm2[tid * 4]; int i2 = ci2[tid * 4];
    #pragma unroll
    for (int wq = 1; wq < 4; ++wq){
      top2_merge(v1, i1, v2, i2, cm1[tid * 4 + wq], ci1[tid * 4 + wq]);
      top2_merge(v1, i1, v2, i2, cm2[tid * 4 + wq], ci2[tid * 4 + wq]);
    }
    size_t row = (size_t)(m0 + tid);
    g_q1v[(size_t)nt * NROW + row] = v1;
    g_q1i[(size_t)nt * NROW + row] = i1;
    g_q2v[(size_t)nt * NROW + row] = v2;
    g_q2i[(size_t)nt * NROW + row] = i2;
  }
}

// ---------------- K4: o-head first GEMM via MFMA (bf16), split-K z=30 -------------
__global__ __launch_bounds__(256) void k_o1(void)
{
  __shared__ unsigned char As[16384];
  __shared__ unsigned char Bs[16384];
  const int tid  = threadIdx.x;
  const int lane = tid & 63;
  const int wv   = tid >> 6;
  const int wr   = wv >> 1, wq = wv & 1;
  const int n0  = blockIdx.x * 128;
  const int m0  = blockIdx.y * 128;
  const int kc0 = blockIdx.z * O1_KZ;

  f32x4 acc[4][4];
  #pragma unroll
  for (int i = 0; i < 4; ++i)
    #pragma unroll
    for (int j = 0; j < 4; ++j)
      acc[i][j] = (f32x4){0.f, 0.f, 0.f, 0.f};

  const int rA = lane >> 3;
  const int c0 = lane & 7;
  for (int kk = 0; kk < O1_KZ; kk += 64){
    int kc = kc0 + kk;
    __syncthreads();
    #pragma unroll
    for (int it = 0; it < 4; ++it){
      int seg = wv * 4 + it;
      int r   = seg * 8 + rA;
      int cs  = c0 ^ (r & 7);
      gload16(g_rawbf + (size_t)(m0 + r) * 15360 + kc + cs * 8, As + seg * 1024);
      gload16(g_wo1bf + (size_t)(n0 + r) * 15360 + kc + cs * 8, Bs + seg * 1024);
    }
    __syncthreads();
    #pragma unroll
    for (int ks = 0; ks < 2; ++ks){
      int q = ks * 4 + (lane >> 4);
      s16x8 a[4];
      #pragma unroll
      for (int i = 0; i < 4; ++i){
        int row = wr * 64 + i * 16 + (lane & 15);
        a[i] = *(const s16x8*)(As + row * 128 + ((q ^ (row & 7)) * 16));
      }
      #pragma unroll
      for (int j = 0; j < 4; ++j){
        int col = wq * 64 + j * 16 + (lane & 15);
        s16x8 b = *(const s16x8*)(Bs + col * 128 + ((q ^ (col & 7)) * 16));
        #pragma unroll
        for (int i = 0; i < 4; ++i)
          acc[i][j] = __builtin_amdgcn_mfma_f32_16x16x32_bf16(a[i], b, acc[i][j], 0, 0, 0);
      }
    }
  }
  const int g = lane >> 4;
  #pragma unroll
  for (int i = 0; i < 4; ++i)
    #pragma unroll
    for (int j = 0; j < 4; ++j)
      #pragma unroll
      for (int r = 0; r < 4; ++r){
        int gm = m0 + wr * 64 + i * 16 + g * 4 + r;
        int gn = n0 + wq * 64 + j * 16 + (lane & 15);
        g_part[((size_t)blockIdx.z * NSAMP + gm) * 512 + gn] = acc[i][j][r];
      }
}

// ---------------- K5: tail: group-merge + margin-refine + o-head MLP --------------
__global__ __launch_bounds__(256) void k_tail(
    const float* __restrict__ wc, const float* __restrict__ bc,
    const float* __restrict__ bo1, const float* __restrict__ wo2,
    const float* __restrict__ bo2, const float* __restrict__ wo3,
    const float* __restrict__ bo3, float* __restrict__ out)
{
  __shared__ float o1f[512];
  __shared__ float o2f[256];
  __shared__ int   bis[60];
  const int s = blockIdx.x;
  const int tid = threadIdx.x;
  if (tid < 60){
    size_t row = (size_t)s * 60 + tid;
    float v1 = -__builtin_inff(); int i1 = 0x7FFFFFFF;
    float v2 = -__builtin_inff(); int i2 = 0x7FFFFFFF;
    for (int g = 0; g < NGRP; ++g){
      top2_merge(v1, i1, v2, i2, g_q1v[(size_t)g * NROW + row], g_q1i[(size_t)g * NROW + row]);
      top2_merge(v1, i1, v2, i2, g_q2v[(size_t)g * NROW + row], g_q2i[(size_t)g * NROW + row]);
    }
    int best = i1;
    // 2-seg residual ~1e-4; delta = 0.012 gives enormous safety margin
    float delta = fmaxf(0.012f, 0.02f * fabsf(v1));
    if (v1 - v2 <= delta){
      float thr = v1 - delta;
      int cand[16]; int cnt = 0;
      for (int g = 0; g < NGRP; ++g){
        float a = g_q1v[(size_t)g * NROW + row];
        if (a >= thr && cnt < 16) cand[cnt++] = g_q1i[(size_t)g * NROW + row];
        float b2v = g_q2v[(size_t)g * NROW + row];
        if (b2v >= thr && cnt < 16) cand[cnt++] = g_q2i[(size_t)g * NROW + row];
      }
      const float* hp = g_h_f32 + row * (size_t)KDIM;
      double bv = -1e300; int bi = 0x7FFFFFFF;
      for (int e = 0; e < cnt; ++e){
        int c = cand[e];
        const float* wp = wc + (size_t)c * KDIM;
        double d = (double)bc[c];
        for (int k2 = 0; k2 < KDIM; k2 += 4){
          float4 hv = *(const float4*)(hp + k2);
          float4 wv4 = *(const float4*)(wp + k2);
          d += (double)hv.x * wv4.x + (double)hv.y * wv4.y
             + (double)hv.z * wv4.z + (double)hv.w * wv4.w;
        }
        if (d > bv || (d == bv && c < bi)){ bv = d; bi = c; }
      }
      best = bi;
    }
    bis[tid] = best;
  }
  for (int j = tid; j < 512; j += 256){
    float a = bo1[j];
    for (int ks = 0; ks < O1_NZ; ++ks) a += g_part[((size_t)ks * NSAMP + s) * 512 + j];
    o1f[j] = fmaxf(a, 0.f);
  }
  __syncthreads();
  {
    float a = bo2[tid];
    const float* wr = wo2 + (size_t)tid * 512;
    for (int i = 0; i < 512; i += 4){
      float4 w4 = *(const float4*)(wr + i);
      a += o1f[i]*w4.x + o1f[i+1]*w4.y + o1f[i+2]*w4.z + o1f[i+3]*w4.w;
    }
    o2f[tid] = fmaxf(a, 0.f);
  }
  __syncthreads();
  if (tid < 127){
    float a = bo3[tid];
    const float* wr = wo3 + (size_t)tid * 256;
    for (int i = 0; i < 256; i += 4){
      float4 w4 = *(const float4*)(wr + i);
      a += o2f[i]*w4.x + o2f[i+1]*w4.y + o2f[i+2]*w4.z + o2f[i+3]*w4.w;
    }
    out[s * 128 + tid] = fmaxf(a, 0.f);
  }
  if (tid == 0){
    int m = bis[0];
    for (int i = 1; i < 60; ++i) m = min(m, bis[i]);
    out[s * 128 + 127] = (float)m;
  }
}

extern "C" void kernel_launch(void* const* d_in, const int* in_sizes, int n_in,
                              void* d_out, int out_size, void* d_ws, size_t ws_size,
                              hipStream_t stream)
{
  (void)d_ws; (void)ws_size; (void)in_sizes; (void)n_in; (void)out_size;
  const int*   x      = (const int*)  d_in[0];
  const float* suit_w = (const float*)d_in[1];
  const float* suit_b = (const float*)d_in[2];
  const float* rank_w = (const float*)d_in[3];
  const float* rank_b = (const float*)d_in[4];
  const float* bns_g  = (const float*)d_in[5];
  const float* bns_b  = (const float*)d_in[6];
  const float* bns_m  = (const float*)d_in[7];
  const float* bns_v  = (const float*)d_in[8];
  const float* bnr_g  = (const float*)d_in[9];
  const float* bnr_b  = (const float*)d_in[10];
  const float* bnr_m  = (const float*)d_in[11];
  const float* bnr_v  = (const float*)d_in[12];
  const float* w1     = (const float*)d_in[13];
  const float* b1     = (const float*)d_in[14];
  const float* w2     = (const float*)d_in[15];
  const float* b2     = (const float*)d_in[16];
  const float* wc     = (const float*)d_in[17];
  const float* bc     = (const float*)d_in[18];
  const float* wo1    = (const float*)d_in[19];
  const float* bo1    = (const float*)d_in[20];
  const float* wo2    = (const float*)d_in[21];
  const float* bo2    = (const float*)d_in[22];
  const float* wo3    = (const float*)d_in[23];
  const float* bo3    = (const float*)d_in[24];
  float* out = (float*)d_out;

  hipLaunchKernelGGL(k_prep, dim3(11520), dim3(256), 0, stream, wc, wo1);
  hipLaunchKernelGGL(k_features, dim3(5760), dim3(256), 0, stream, x,
                     suit_w, suit_b, rank_w, rank_b,
                     bns_g, bns_b, bns_m, bns_v, bnr_g, bnr_b, bnr_m, bnr_v,
                     w1, b1, w2, b2);
  hipLaunchKernelGGL(k_logits, dim3(NTILE_N * NTILE_M), dim3(512), 0, stream, bc);
  hipLaunchKernelGGL(k_o1, dim3(4, 3, O1_NZ), dim3(256), 0, stream);
  hipLaunchKernelGGL(k_tail, dim3(NSAMP), dim3(256), 0, stream,
                     wc, bc, bo1, wo2, bo2, wo3, bo3, out);
}

// Round 19
// 966.112 us; speedup vs baseline: 2.1259x; 2.1259x over previous
//
#include <hip/hip_runtime.h>

#define NSAMP 384
#define NCOMBO 60
#define NROW 23040
#define KDIM 512
#define NCLS 7463
#define NCLSP 7680
#define NTILE_N 30
#define NTILE_M 180
#define O1_NZ 60
#define O1_KZ 256

typedef short s16x8 __attribute__((ext_vector_type(8)));
typedef short s16x4 __attribute__((ext_vector_type(4)));
typedef float f32x4 __attribute__((ext_vector_type(4)));

// ---- module-level scratch (R16 layout; every byte rewritten each call) ----
__device__ unsigned short g_wc_hi[NCLSP * KDIM];
__device__ unsigned short g_wc_lo[NCLSP * KDIM];
__device__ unsigned short g_h_hi[NROW * KDIM];
__device__ unsigned short g_h_lo[NROW * KDIM];
__device__ unsigned short g_rawbf[NROW * 256];          // == [NSAMP][15360]
__device__ unsigned short g_wo1bf[512 * 15360];
__device__ float          g_pmax[NTILE_N * NROW];       // [nt][row]
__device__ int            g_pidx[NTILE_N * NROW];
__device__ float          g_part[O1_NZ * NSAMP * 512];

__device__ __forceinline__ float bf2f(unsigned short u){
  union { unsigned int i; float f; } v; v.i = ((unsigned int)u) << 16; return v.f;
}
__device__ __forceinline__ unsigned short f2bf(float f){
  union { float f; unsigned int i; } v; v.f = f;
  unsigned int u = v.i;
  unsigned int r = (u + 0x7FFFu + ((u >> 16) & 1u)) >> 16;
  return (unsigned short)r;
}
__device__ __forceinline__ void gload16(const void* g, void* l){
  __builtin_amdgcn_global_load_lds((const __attribute__((address_space(1))) void*)g,
                                   (__attribute__((address_space(3))) void*)l, 16, 0, 0);
}

// ---------------- K1: merged prep (wc/wo1 -> bf16) + per-combo features -----------
// blocks [0, 11520): prep; blocks [11520, 17280): features. Independent workloads,
// one launch -> co-scheduled (prep is memory-bound, features VALU-bound).
__global__ __launch_bounds__(256) void k_front(
    const int* __restrict__ x,
    const float* __restrict__ wc, const float* __restrict__ wo1,
    const float* __restrict__ suit_w, const float* __restrict__ suit_b,
    const float* __restrict__ rank_w, const float* __restrict__ rank_b,
    const float* __restrict__ bns_g, const float* __restrict__ bns_b,
    const float* __restrict__ bns_m, const float* __restrict__ bns_v,
    const float* __restrict__ bnr_g, const float* __restrict__ bnr_b,
    const float* __restrict__ bnr_m, const float* __restrict__ bnr_v,
    const float* __restrict__ w1, const float* __restrict__ b1,
    const float* __restrict__ w2, const float* __restrict__ b2)
{
  __shared__ float raw_s[4][256];
  __shared__ float h1_s[4][512];
  __shared__ float w1s[512];
  __shared__ float w2s[1024];
  __shared__ float b1s[32];
  __shared__ float b2s[32];
  const int tid = threadIdx.x;
  const int bb  = blockIdx.x;
  if (bb < 11520){
    // ---- prep branch ----
    if (bb < 3840){
      int idx = (bb * 256 + tid) * 4;
      float4 w = {0.f, 0.f, 0.f, 0.f};
      if (idx < NCLS * KDIM) w = *(const float4*)(wc + idx);
      s16x4 hi, lo;
      float wv[4] = {w.x, w.y, w.z, w.w};
      #pragma unroll
      for (int i = 0; i < 4; ++i){
        unsigned short h = f2bf(wv[i]);
        hi[i] = (short)h;
        lo[i] = (short)f2bf(wv[i] - bf2f(h));
      }
      *(s16x4*)(g_wc_hi + idx) = hi;
      *(s16x4*)(g_wc_lo + idx) = lo;
    } else {
      int idx = ((bb - 3840) * 256 + tid) * 4;   // covers 512*15360 exactly
      float4 w = *(const float4*)(wo1 + idx);
      s16x4 v;
      v[0] = (short)f2bf(w.x); v[1] = (short)f2bf(w.y);
      v[2] = (short)f2bf(w.z); v[3] = (short)f2bf(w.w);
      *(s16x4*)(g_wo1bf + idx) = v;
    }
    return;
  }
  // ---- features branch ----
  const int fb   = bb - 11520;               // 0..5759
  const int lane = tid & 63;
  const int wv   = tid >> 6;
  const int combo = fb * 4 + wv;
  const int s = combo / 60;
  const int k = combo % 60;
  const int hp = k / 10, bt = k % 10;
  const int HP0[6]  = {0,0,0,1,1,2}, HP1[6] = {1,2,3,2,3,3};
  const int BT0[10] = {4,4,4,4,4,4,5,5,5,6};
  const int BT1[10] = {5,5,5,6,6,7,6,6,7,7};
  const int BT2[10] = {6,7,8,7,8,8,7,8,8,8};
  int cards[5] = {HP0[hp], HP1[hp], BT0[bt], BT1[bt], BT2[bt]};
  const int* xp = x + s * 18;
  int rk[5], st[5];
  #pragma unroll
  for (int c = 0; c < 5; ++c){ rk[c] = xp[2*cards[c]]; st[c] = xp[2*cards[c] + 1]; }

  // cooperative weight preload (visible after the first __syncthreads below)
  w1s[tid]       = w1[tid];
  w1s[tid + 256] = w1[tid + 256];
  #pragma unroll
  for (int i = 0; i < 4; ++i) w2s[tid + i * 256] = w2[tid + i * 256];
  if (tid < 32){ b1s[tid] = b1[tid]; b2s[tid] = b2[tid]; }

  {
    s16x4 rv;
    #pragma unroll
    for (int i = 0; i < 4; ++i){
      int e = lane * 4 + i;
      int o = e >> 4, l = e & 15;
      float v;
      if (l < 11){
        float a = 0.f;
        #pragma unroll
        for (int c = 0; c < 5; ++c){
          int d = rk[c] - l;
          if (d >= 0 && d < 5) a += rank_w[o*25 + c*5 + d];
        }
        a += rank_b[o];
        float inv = bnr_g[o] / sqrtf(bnr_v[o] + 1e-5f);
        v = a * inv + (bnr_b[o] - bnr_m[o] * inv);
      } else {
        int j = l - 11;
        float a = suit_b[o];
        #pragma unroll
        for (int c = 0; c < 5; ++c) if (st[c] == j) a += suit_w[o*5 + c];
        float inv = bns_g[o] / sqrtf(bns_v[o] + 1e-5f);
        v = a * inv + (bns_b[o] - bns_m[o] * inv);
      }
      v = fmaxf(v, 0.f);
      raw_s[wv][e] = v;
      rv[i] = (short)f2bf(v);
    }
    *(s16x4*)(g_rawbf + (size_t)s * 15360 + k * 256 + lane * 4) = rv;
  }
  __syncthreads();
  #pragma unroll
  for (int i = 0; i < 8; ++i){
    int e = lane + 64 * i;
    int o = e >> 5, j = e & 31;
    float a = b1s[j];
    #pragma unroll
    for (int l = 0; l < 16; ++l) a += raw_s[wv][o*16 + l] * w1s[j*16 + l];
    h1_s[wv][e] = fmaxf(a, 0.f);
  }
  __syncthreads();
  {
    s16x8 hv, lv;
    #pragma unroll
    for (int i = 0; i < 8; ++i){
      int e = lane * 8 + i;
      int o = e >> 5, j = e & 31;
      float a = b2s[j];
      #pragma unroll
      for (int l = 0; l < 32; ++l) a += h1_s[wv][o*32 + l] * w2s[j*32 + l];
      a = fmaxf(a, 0.f);
      unsigned short h = f2bf(a);
      hv[i] = (short)h;
      lv[i] = (short)f2bf(a - bf2f(h));
    }
    *(s16x8*)(g_h_hi + (size_t)combo * 512 + lane * 8) = hv;
    *(s16x8*)(g_h_lo + (size_t)combo * 512 + lane * 8) = lv;
  }
}

// ---------------- K2: logits GEMM, R16 byte-exact (measured 817us) ----------------
// BM=128, BN=256, BK=32; 8 waves (2M x 4N), per-wave 64x64 out; LDS 2 x 24KB dbuf;
// virtual K = 1536 interleaved k-first (t -> kc=t/3*32, seg=t%3); counted
// vmcnt(3), never 0 until tail; m-fastest grid.
__global__ __launch_bounds__(512, 4) void k_logits(const float* __restrict__ bc)
{
  __shared__ unsigned char lds[49152];
  const int tid  = threadIdx.x;
  const int lane = tid & 63;
  const int wv   = tid >> 6;                 // 0..7
  const int wm   = wv >> 2, wn = wv & 3;     // 2M x 4N
  const int blk  = blockIdx.x;               // 5400 = 30 nt x 180 mt, m-fastest
  const int nt   = blk / NTILE_M;
  const int mt   = blk % NTILE_M;
  const int m0 = mt * 128;
  const int n0 = nt * 256;

  f32x4 acc[4][4];
  #pragma unroll
  for (int i = 0; i < 4; ++i)
    #pragma unroll
    for (int j = 0; j < 4; ++j)
      acc[i][j] = (f32x4){0.f, 0.f, 0.f, 0.f};

  const int rS = wv * 16 + (lane >> 2);              // 0..127
  const int cS = (lane & 3) ^ ((lane >> 3) & 3);     // pre-swizzled source chunk
  auto stage = [&](int buf, int t){
    const int p = t / 3, seg = t - p * 3;
    const int kc = p * 32;
    const unsigned short* As = (seg < 2) ? g_h_hi : g_h_lo;
    const unsigned short* Bs = (seg == 1) ? g_wc_lo : g_wc_hi;
    const unsigned base = buf * 24576 + wv * 1024;
    gload16(As + (size_t)(m0 + rS) * KDIM + kc + cS * 8, lds + base);
    gload16(Bs + (size_t)(n0 + rS) * KDIM + kc + cS * 8, lds + base + 8192);
    gload16(Bs + (size_t)(n0 + 128 + rS) * KDIM + kc + cS * 8, lds + base + 16384);
  };

  stage(0, 0);
  stage(1, 1);
  asm volatile("s_waitcnt vmcnt(3)" ::: "memory");   // tile0's 3 loads done
  __builtin_amdgcn_sched_barrier(0);
  __builtin_amdgcn_s_barrier();
  asm volatile("" ::: "memory");

  const int q = lane >> 4;                   // 16B k-chunk 0..3
  #pragma unroll 1
  for (int t = 0; t < 48; ++t){
    const unsigned cb = (unsigned)(t & 1) * 24576;
    s16x8 af[4], bf[4];
    #pragma unroll
    for (int i = 0; i < 4; ++i){
      int row = wm * 64 + i * 16 + (lane & 15);
      af[i] = *(const s16x8*)(lds + cb + row * 64 + ((q ^ ((row >> 1) & 3)) << 4));
    }
    #pragma unroll
    for (int j = 0; j < 4; ++j){
      int row = wn * 64 + j * 16 + (lane & 15);
      bf[j] = *(const s16x8*)(lds + cb + 8192 + row * 64 + ((q ^ ((row >> 1) & 3)) << 4));
    }
    __builtin_amdgcn_s_setprio(1);
    #pragma unroll
    for (int i = 0; i < 4; ++i)
      #pragma unroll
      for (int j = 0; j < 4; ++j)
        acc[i][j] = __builtin_amdgcn_mfma_f32_16x16x32_bf16(af[i], bf[j], acc[i][j], 0, 0, 0);
    __builtin_amdgcn_s_setprio(0);
    __builtin_amdgcn_sched_barrier(0);
    __builtin_amdgcn_s_barrier();            // all waves done reading buffer cb
    asm volatile("" ::: "memory");
    if (t + 2 < 48){
      stage(t & 1, t + 2);                   // overwrite cb; loads fly across barriers
      asm volatile("s_waitcnt vmcnt(3)" ::: "memory");  // tile t+1 confirmed
    } else {
      asm volatile("s_waitcnt vmcnt(0)" ::: "memory");  // tail drain
    }
    __builtin_amdgcn_sched_barrier(0);
    __builtin_amdgcn_s_barrier();
    asm volatile("" ::: "memory");
  }

  // epilogue: + bc, per-row argmax over this 256-col tile (ties -> lowest index)
  float* cmax = (float*)lds;                 // [128 rows][4 wn]
  int*   cidx = (int*)(lds + 2048);
  const int g = lane >> 4;
  #pragma unroll
  for (int i = 0; i < 4; ++i){
    #pragma unroll
    for (int r = 0; r < 4; ++r){
      float bv = -__builtin_inff(); int bi = 0x7FFFFFFF;
      #pragma unroll
      for (int j = 0; j < 4; ++j){
        int col = n0 + wn * 64 + j * 16 + (lane & 15);
        if (col < NCLS){
          float v = acc[i][j][r] + bc[col];
          if (v > bv){ bv = v; bi = col; }
        }
      }
      for (int s = 1; s < 16; s <<= 1){
        float ov = __shfl_xor(bv, s);
        int   oi = __shfl_xor(bi, s);
        if (ov > bv || (ov == bv && oi < bi)){ bv = ov; bi = oi; }
      }
      if ((lane & 15) == 0){
        int rloc = wm * 64 + i * 16 + g * 4 + r;
        cmax[rloc * 4 + wn] = bv;
        cidx[rloc * 4 + wn] = bi;
      }
    }
  }
  __syncthreads();
  if (tid < 128){
    float bv = cmax[tid * 4]; int bi = cidx[tid * 4];
    #pragma unroll
    for (int wq = 1; wq < 4; ++wq){
      float v = cmax[tid * 4 + wq]; int i1 = cidx[tid * 4 + wq];
      if (v > bv || (v == bv && i1 < bi)){ bv = v; bi = i1; }
    }
    size_t row = (size_t)(m0 + tid);
    g_pmax[(size_t)nt * NROW + row] = bv;
    g_pidx[(size_t)nt * NROW + row] = bi;
  }
}

// ---------------- K4: o-head first GEMM via MFMA (bf16), split-K z=60 -------------
__global__ __launch_bounds__(256) void k_o1(void)
{
  __shared__ unsigned char As[16384];
  __shared__ unsigned char Bs[16384];
  const int tid  = threadIdx.x;
  const int lane = tid & 63;
  const int wv   = tid >> 6;
  const int wr   = wv >> 1, wq = wv & 1;
  const int n0  = blockIdx.x * 128;
  const int m0  = blockIdx.y * 128;
  const int kc0 = blockIdx.z * O1_KZ;

  f32x4 acc[4][4];
  #pragma unroll
  for (int i = 0; i < 4; ++i)
    #pragma unroll
    for (int j = 0; j < 4; ++j)
      acc[i][j] = (f32x4){0.f, 0.f, 0.f, 0.f};

  const int rA = lane >> 3;
  const int c0 = lane & 7;
  for (int kk = 0; kk < O1_KZ; kk += 64){
    int kc = kc0 + kk;
    __syncthreads();
    #pragma unroll
    for (int it = 0; it < 4; ++it){
      int seg = wv * 4 + it;
      int r   = seg * 8 + rA;
      int cs  = c0 ^ (r & 7);
      gload16(g_rawbf + (size_t)(m0 + r) * 15360 + kc + cs * 8, As + seg * 1024);
      gload16(g_wo1bf + (size_t)(n0 + r) * 15360 + kc + cs * 8, Bs + seg * 1024);
    }
    __syncthreads();
    #pragma unroll
    for (int ks = 0; ks < 2; ++ks){
      int q = ks * 4 + (lane >> 4);
      s16x8 a[4];
      #pragma unroll
      for (int i = 0; i < 4; ++i){
        int row = wr * 64 + i * 16 + (lane & 15);
        a[i] = *(const s16x8*)(As + row * 128 + ((q ^ (row & 7)) * 16));
      }
      #pragma unroll
      for (int j = 0; j < 4; ++j){
        int col = wq * 64 + j * 16 + (lane & 15);
        s16x8 b = *(const s16x8*)(Bs + col * 128 + ((q ^ (col & 7)) * 16));
        #pragma unroll
        for (int i = 0; i < 4; ++i)
          acc[i][j] = __builtin_amdgcn_mfma_f32_16x16x32_bf16(a[i], b, acc[i][j], 0, 0, 0);
      }
    }
  }
  const int g = lane >> 4;
  #pragma unroll
  for (int i = 0; i < 4; ++i)
    #pragma unroll
    for (int j = 0; j < 4; ++j)
      #pragma unroll
      for (int r = 0; r < 4; ++r){
        int gm = m0 + wr * 64 + i * 16 + g * 4 + r;
        int gn = n0 + wq * 64 + j * 16 + (lane & 15);
        g_part[((size_t)blockIdx.z * NSAMP + gm) * 512 + gn] = acc[i][j][r];
      }
}

// ---------------- K5: tail: split-K reduce + 512->256->127 MLP + best-combine -----
__global__ __launch_bounds__(256) void k_tail(
    const float* __restrict__ bo1, const float* __restrict__ wo2,
    const float* __restrict__ bo2, const float* __restrict__ wo3,
    const float* __restrict__ bo3, float* __restrict__ out)
{
  __shared__ float o1f[512];
  __shared__ float o2f[256];
  __shared__ int   bis[60];
  const int s = blockIdx.x;
  const int tid = threadIdx.x;
  if (tid < 60){
    size_t row = (size_t)s * 60 + tid;
    float bv = -__builtin_inff(); int bi = 0x7FFFFFFF;
    for (int qn = 0; qn < NTILE_N; ++qn){
      float v = g_pmax[(size_t)qn * NROW + row];
      int   i = g_pidx[(size_t)qn * NROW + row];
      if (v > bv || (v == bv && i < bi)){ bv = v; bi = i; }
    }
    bis[tid] = bi;
  }
  for (int j = tid; j < 512; j += 256){
    float a = bo1[j];
    for (int ks = 0; ks < O1_NZ; ++ks) a += g_part[((size_t)ks * NSAMP + s) * 512 + j];
    o1f[j] = fmaxf(a, 0.f);
  }
  __syncthreads();
  {
    float a = bo2[tid];
    const float* wr = wo2 + (size_t)tid * 512;
    for (int i = 0; i < 512; i += 4){
      float4 w4 = *(const float4*)(wr + i);
      a += o1f[i]*w4.x + o1f[i+1]*w4.y + o1f[i+2]*w4.z + o1f[i+3]*w4.w;
    }
    o2f[tid] = fmaxf(a, 0.f);
  }
  __syncthreads();
  if (tid < 127){
    float a = bo3[tid];
    const float* wr = wo3 + (size_t)tid * 256;
    for (int i = 0; i < 256; i += 4){
      float4 w4 = *(const float4*)(wr + i);
      a += o2f[i]*w4.x + o2f[i+1]*w4.y + o2f[i+2]*w4.z + o2f[i+3]*w4.w;
    }
    out[s * 128 + tid] = fmaxf(a, 0.f);
  }
  if (tid == 0){
    int m = bis[0];
    for (int i = 1; i < 60; ++i) m = min(m, bis[i]);
    out[s * 128 + 127] = (float)m;
  }
}

extern "C" void kernel_launch(void* const* d_in, const int* in_sizes, int n_in,
                              void* d_out, int out_size, void* d_ws, size_t ws_size,
                              hipStream_t stream)
{
  (void)d_ws; (void)ws_size; (void)in_sizes; (void)n_in; (void)out_size;
  const int*   x      = (const int*)  d_in[0];
  const float* suit_w = (const float*)d_in[1];
  const float* suit_b = (const float*)d_in[2];
  const float* rank_w = (const float*)d_in[3];
  const float* rank_b = (const float*)d_in[4];
  const float* bns_g  = (const float*)d_in[5];
  const float* bns_b  = (const float*)d_in[6];
  const float* bns_m  = (const float*)d_in[7];
  const float* bns_v  = (const float*)d_in[8];
  const float* bnr_g  = (const float*)d_in[9];
  const float* bnr_b  = (const float*)d_in[10];
  const float* bnr_m  = (const float*)d_in[11];
  const float* bnr_v  = (const float*)d_in[12];
  const float* w1     = (const float*)d_in[13];
  const float* b1     = (const float*)d_in[14];
  const float* w2     = (const float*)d_in[15];
  const float* b2     = (const float*)d_in[16];
  const float* wc     = (const float*)d_in[17];
  const float* bc     = (const float*)d_in[18];
  const float* wo1    = (const float*)d_in[19];
  const float* bo1    = (const float*)d_in[20];
  const float* wo2    = (const float*)d_in[21];
  const float* bo2    = (const float*)d_in[22];
  const float* wo3    = (const float*)d_in[23];
  const float* bo3    = (const float*)d_in[24];
  float* out = (float*)d_out;

  hipLaunchKernelGGL(k_front, dim3(17280), dim3(256), 0, stream, x, wc, wo1,
                     suit_w, suit_b, rank_w, rank_b,
                     bns_g, bns_b, bns_m, bns_v, bnr_g, bnr_b, bnr_m, bnr_v,
                     w1, b1, w2, b2);
  hipLaunchKernelGGL(k_logits, dim3(NTILE_N * NTILE_M), dim3(512), 0, stream, bc);
  hipLaunchKernelGGL(k_o1, dim3(4, 3, O1_NZ), dim3(256), 0, stream);
  hipLaunchKernelGGL(k_tail, dim3(NSAMP), dim3(256), 0, stream,
                     bo1, wo2, bo2, wo3, bo3, out);
}

// Round 20
// 937.382 us; speedup vs baseline: 2.1911x; 1.0306x over previous
//
#include <hip/hip_runtime.h>

#define NSAMP 384
#define NCOMBO 60
#define NROW 23040
#define KDIM 512
#define NCLS 7463
#define NCLSP 7680
#define NTILE_N 30
#define NTILE_M 180
#define O1_NZ 30
#define O1_KZ 256

typedef short s16x8 __attribute__((ext_vector_type(8)));
typedef short s16x4 __attribute__((ext_vector_type(4)));
typedef float f32x4 __attribute__((ext_vector_type(4)));

// ---- module-level scratch (fast-family layout; every byte rewritten per call) ----
__device__ unsigned short g_wc_hi[NCLSP * KDIM];
__device__ unsigned short g_wc_lo[NCLSP * KDIM];
__device__ unsigned short g_h_hi[NROW * KDIM];
__device__ unsigned short g_h_lo[NROW * KDIM];
__device__ unsigned short g_rawbf[NROW * 256];          // == [NSAMP][15360]
__device__ unsigned short g_wo1bf[512 * 15360];
__device__ float          g_pmax[NTILE_N * NROW];       // [nt][row]
__device__ int            g_pidx[NTILE_N * NROW];
__device__ float          g_part[O1_NZ * NSAMP * 512];

__device__ __forceinline__ float bf2f(unsigned short u){
  union { unsigned int i; float f; } v; v.i = ((unsigned int)u) << 16; return v.f;
}
__device__ __forceinline__ unsigned short f2bf(float f){
  union { float f; unsigned int i; } v; v.f = f;
  unsigned int u = v.i;
  unsigned int r = (u + 0x7FFFu + ((u >> 16) & 1u)) >> 16;
  return (unsigned short)r;
}
__device__ __forceinline__ void gload16(const void* g, void* l){
  __builtin_amdgcn_global_load_lds((const __attribute__((address_space(1))) void*)g,
                                   (__attribute__((address_space(3))) void*)l, 16, 0, 0);
}

// ---------------- K0: wc -> bf16 hi/lo (pad to 7680) AND wo1 -> bf16 --------------
__global__ __launch_bounds__(256) void k_prep(const float* __restrict__ wc,
                                              const float* __restrict__ wo1)
{
  int b = blockIdx.x;
  if (b < 3840){
    int idx = (b * 256 + threadIdx.x) * 4;
    float4 w = {0.f, 0.f, 0.f, 0.f};
    if (idx < NCLS * KDIM) w = *(const float4*)(wc + idx);
    s16x4 hi, lo;
    float wv[4] = {w.x, w.y, w.z, w.w};
    #pragma unroll
    for (int i = 0; i < 4; ++i){
      unsigned short h = f2bf(wv[i]);
      hi[i] = (short)h;
      lo[i] = (short)f2bf(wv[i] - bf2f(h));
    }
    *(s16x4*)(g_wc_hi + idx) = hi;
    *(s16x4*)(g_wc_lo + idx) = lo;
  } else {
    int idx = ((b - 3840) * 256 + threadIdx.x) * 4;   // covers 512*15360 exactly
    float4 w = *(const float4*)(wo1 + idx);
    s16x4 v;
    v[0] = (short)f2bf(w.x); v[1] = (short)f2bf(w.y);
    v[2] = (short)f2bf(w.z); v[3] = (short)f2bf(w.w);
    *(s16x4*)(g_wo1bf + idx) = v;
  }
}

// ---------------- K1: per-combo features -> h hi/lo + raw bf16 ----------------
__global__ __launch_bounds__(256) void k_features(
    const int* __restrict__ x,
    const float* __restrict__ suit_w, const float* __restrict__ suit_b,
    const float* __restrict__ rank_w, const float* __restrict__ rank_b,
    const float* __restrict__ bns_g, const float* __restrict__ bns_b,
    const float* __restrict__ bns_m, const float* __restrict__ bns_v,
    const float* __restrict__ bnr_g, const float* __restrict__ bnr_b,
    const float* __restrict__ bnr_m, const float* __restrict__ bnr_v,
    const float* __restrict__ w1, const float* __restrict__ b1,
    const float* __restrict__ w2, const float* __restrict__ b2)
{
  __shared__ float raw_s[4][256];
  __shared__ float h1_s[4][512];
  __shared__ float w1s[512];
  __shared__ float w2s[1024];
  __shared__ float b1s[32];
  __shared__ float b2s[32];
  const int tid  = threadIdx.x;
  const int lane = tid & 63;
  const int wv   = tid >> 6;
  const int combo = blockIdx.x * 4 + wv;
  const int s = combo / 60;
  const int k = combo % 60;
  const int hp = k / 10, bt = k % 10;
  const int HP0[6]  = {0,0,0,1,1,2}, HP1[6] = {1,2,3,2,3,3};
  const int BT0[10] = {4,4,4,4,4,4,5,5,5,6};
  const int BT1[10] = {5,5,5,6,6,7,6,6,7,7};
  const int BT2[10] = {6,7,8,7,8,8,7,8,8,8};
  int cards[5] = {HP0[hp], HP1[hp], BT0[bt], BT1[bt], BT2[bt]};
  const int* xp = x + s * 18;
  int rk[5], st[5];
  #pragma unroll
  for (int c = 0; c < 5; ++c){ rk[c] = xp[2*cards[c]]; st[c] = xp[2*cards[c] + 1]; }

  // cooperative weight preload (visible after the first __syncthreads below)
  w1s[tid]       = w1[tid];
  w1s[tid + 256] = w1[tid + 256];
  #pragma unroll
  for (int i = 0; i < 4; ++i) w2s[tid + i * 256] = w2[tid + i * 256];
  if (tid < 32){ b1s[tid] = b1[tid]; b2s[tid] = b2[tid]; }

  {
    s16x4 rv;
    #pragma unroll
    for (int i = 0; i < 4; ++i){
      int e = lane * 4 + i;
      int o = e >> 4, l = e & 15;
      float v;
      if (l < 11){
        float a = 0.f;
        #pragma unroll
        for (int c = 0; c < 5; ++c){
          int d = rk[c] - l;
          if (d >= 0 && d < 5) a += rank_w[o*25 + c*5 + d];
        }
        a += rank_b[o];
        float inv = bnr_g[o] / sqrtf(bnr_v[o] + 1e-5f);
        v = a * inv + (bnr_b[o] - bnr_m[o] * inv);
      } else {
        int j = l - 11;
        float a = suit_b[o];
        #pragma unroll
        for (int c = 0; c < 5; ++c) if (st[c] == j) a += suit_w[o*5 + c];
        float inv = bns_g[o] / sqrtf(bns_v[o] + 1e-5f);
        v = a * inv + (bns_b[o] - bns_m[o] * inv);
      }
      v = fmaxf(v, 0.f);
      raw_s[wv][e] = v;
      rv[i] = (short)f2bf(v);
    }
    *(s16x4*)(g_rawbf + (size_t)s * 15360 + k * 256 + lane * 4) = rv;
  }
  __syncthreads();
  #pragma unroll
  for (int i = 0; i < 8; ++i){
    int e = lane + 64 * i;
    int o = e >> 5, j = e & 31;
    float a = b1s[j];
    #pragma unroll
    for (int l = 0; l < 16; ++l) a += raw_s[wv][o*16 + l] * w1s[j*16 + l];
    h1_s[wv][e] = fmaxf(a, 0.f);
  }
  __syncthreads();
  {
    s16x8 hv, lv;
    #pragma unroll
    for (int i = 0; i < 8; ++i){
      int e = lane * 8 + i;
      int o = e >> 5, j = e & 31;
      float a = b2s[j];
      #pragma unroll
      for (int l = 0; l < 32; ++l) a += h1_s[wv][o*32 + l] * w2s[j*32 + l];
      a = fmaxf(a, 0.f);
      unsigned short h = f2bf(a);
      hv[i] = (short)h;
      lv[i] = (short)f2bf(a - bf2f(h));
    }
    *(s16x8*)(g_h_hi + (size_t)combo * 512 + lane * 8) = hv;
    *(s16x8*)(g_h_lo + (size_t)combo * 512 + lane * 8) = lv;
  }
}

// ---------------- K2: fused logits GEMM (blocks <5400) + o-head GEMM (>=5400) -----
// Logits part = R16/R19 byte-exact (measured 817us x3): BM=128, BN=256, BK=32;
// 8 waves (2M x 4N); LDS 2x24KB dbuf; virtual K=1536 k-first (t -> kc=t/3*32,
// seg=t%3); counted vmcnt(3); m-fastest order. o1 part: 180 blocks appended,
// each = two 4-wave teams, one z-slice each (BK=32, 16KB LDS/team), filling the
// logits dispatch tail that previously ran as a separate kernel.
__global__ __launch_bounds__(512, 4) void k_fused(const float* __restrict__ bc)
{
  __shared__ unsigned char lds[49152];
  const int tid  = threadIdx.x;
  const int blk  = blockIdx.x;

  if (blk >= NTILE_N * NTILE_M){
    // ---------------- o-head branch ----------------
    const int idx  = blk - NTILE_N * NTILE_M;   // 0..179
    const int nb   = idx & 3;                   // 4 n-tiles
    const int mb   = (idx >> 2) % 3;            // 3 m-tiles
    const int zp   = idx / 12;                  // 0..14
    const int team = tid >> 8;                  // 0/1
    const int ttid = tid & 255;
    const int z    = zp * 2 + team;             // 0..29
    const int lane = ttid & 63;
    const int twv  = ttid >> 6;                 // 0..3
    const int wr   = twv >> 1, wq = twv & 1;
    const int n0   = nb * 128;
    const int m0   = mb * 128;
    const int kc0  = z * O1_KZ;
    unsigned char* As = lds + team * 16384;
    unsigned char* Bs = As + 8192;

    f32x4 acc[4][4];
    #pragma unroll
    for (int i = 0; i < 4; ++i)
      #pragma unroll
      for (int j = 0; j < 4; ++j)
        acc[i][j] = (f32x4){0.f, 0.f, 0.f, 0.f};

    const int rA = lane >> 2;                   // 0..15
    const int c0 = lane & 3;
    for (int kk = 0; kk < O1_KZ; kk += 32){
      int kc = kc0 + kk;
      __syncthreads();
      #pragma unroll
      for (int it = 0; it < 2; ++it){
        int seg = twv * 2 + it;                 // 0..7 (wave-uniform)
        int r   = seg * 16 + rA;                // 0..127
        int cs  = c0 ^ ((rA >> 1) & 3);         // pre-swizzled source chunk
        unsigned lb = (unsigned)(seg * 1024);
        gload16(g_rawbf + (size_t)(m0 + r) * 15360 + kc + cs * 8, As + lb);
        gload16(g_wo1bf + (size_t)(n0 + r) * 15360 + kc + cs * 8, Bs + lb);
      }
      __syncthreads();
      const int q = lane >> 4;
      s16x8 a[4];
      #pragma unroll
      for (int i = 0; i < 4; ++i){
        int row = wr * 64 + i * 16 + (lane & 15);
        a[i] = *(const s16x8*)(As + row * 64 + ((q ^ ((row >> 1) & 3)) * 16));
      }
      #pragma unroll
      for (int j = 0; j < 4; ++j){
        int col = wq * 64 + j * 16 + (lane & 15);
        s16x8 b = *(const s16x8*)(Bs + col * 64 + ((q ^ ((col >> 1) & 3)) * 16));
        #pragma unroll
        for (int i = 0; i < 4; ++i)
          acc[i][j] = __builtin_amdgcn_mfma_f32_16x16x32_bf16(a[i], b, acc[i][j], 0, 0, 0);
      }
    }
    const int g = lane >> 4;
    #pragma unroll
    for (int i = 0; i < 4; ++i)
      #pragma unroll
      for (int j = 0; j < 4; ++j)
        #pragma unroll
        for (int r = 0; r < 4; ++r){
          int gm = m0 + wr * 64 + i * 16 + g * 4 + r;
          int gn = n0 + wq * 64 + j * 16 + (lane & 15);
          g_part[((size_t)z * NSAMP + gm) * 512 + gn] = acc[i][j][r];
        }
    return;
  }

  // ---------------- logits branch (byte-exact R16) ----------------
  const int lane = tid & 63;
  const int wv   = tid >> 6;                 // 0..7
  const int wm   = wv >> 2, wn = wv & 3;     // 2M x 4N
  const int nt   = blk / NTILE_M;
  const int mt   = blk % NTILE_M;
  const int m0 = mt * 128;
  const int n0 = nt * 256;

  f32x4 acc[4][4];
  #pragma unroll
  for (int i = 0; i < 4; ++i)
    #pragma unroll
    for (int j = 0; j < 4; ++j)
      acc[i][j] = (f32x4){0.f, 0.f, 0.f, 0.f};

  const int rS = wv * 16 + (lane >> 2);              // 0..127
  const int cS = (lane & 3) ^ ((lane >> 3) & 3);     // pre-swizzled source chunk
  auto stage = [&](int buf, int t){
    const int p = t / 3, seg = t - p * 3;
    const int kc = p * 32;
    const unsigned short* As = (seg < 2) ? g_h_hi : g_h_lo;
    const unsigned short* Bs = (seg == 1) ? g_wc_lo : g_wc_hi;
    const unsigned base = buf * 24576 + wv * 1024;
    gload16(As + (size_t)(m0 + rS) * KDIM + kc + cS * 8, lds + base);
    gload16(Bs + (size_t)(n0 + rS) * KDIM + kc + cS * 8, lds + base + 8192);
    gload16(Bs + (size_t)(n0 + 128 + rS) * KDIM + kc + cS * 8, lds + base + 16384);
  };

  stage(0, 0);
  stage(1, 1);
  asm volatile("s_waitcnt vmcnt(3)" ::: "memory");   // tile0's 3 loads done
  __builtin_amdgcn_sched_barrier(0);
  __builtin_amdgcn_s_barrier();
  asm volatile("" ::: "memory");

  const int q = lane >> 4;                   // 16B k-chunk 0..3
  #pragma unroll 1
  for (int t = 0; t < 48; ++t){
    const unsigned cb = (unsigned)(t & 1) * 24576;
    s16x8 af[4], bf[4];
    #pragma unroll
    for (int i = 0; i < 4; ++i){
      int row = wm * 64 + i * 16 + (lane & 15);
      af[i] = *(const s16x8*)(lds + cb + row * 64 + ((q ^ ((row >> 1) & 3)) << 4));
    }
    #pragma unroll
    for (int j = 0; j < 4; ++j){
      int row = wn * 64 + j * 16 + (lane & 15);
      bf[j] = *(const s16x8*)(lds + cb + 8192 + row * 64 + ((q ^ ((row >> 1) & 3)) << 4));
    }
    __builtin_amdgcn_s_setprio(1);
    #pragma unroll
    for (int i = 0; i < 4; ++i)
      #pragma unroll
      for (int j = 0; j < 4; ++j)
        acc[i][j] = __builtin_amdgcn_mfma_f32_16x16x32_bf16(af[i], bf[j], acc[i][j], 0, 0, 0);
    __builtin_amdgcn_s_setprio(0);
    __builtin_amdgcn_sched_barrier(0);
    __builtin_amdgcn_s_barrier();            // all waves done reading buffer cb
    asm volatile("" ::: "memory");
    if (t + 2 < 48){
      stage(t & 1, t + 2);                   // overwrite cb; loads fly across barriers
      asm volatile("s_waitcnt vmcnt(3)" ::: "memory");  // tile t+1 confirmed
    } else {
      asm volatile("s_waitcnt vmcnt(0)" ::: "memory");  // tail drain
    }
    __builtin_amdgcn_sched_barrier(0);
    __builtin_amdgcn_s_barrier();
    asm volatile("" ::: "memory");
  }

  // epilogue: + bc, per-row argmax over this 256-col tile (ties -> lowest index)
  float* cmax = (float*)lds;                 // [128 rows][4 wn]
  int*   cidx = (int*)(lds + 2048);
  const int g = lane >> 4;
  #pragma unroll
  for (int i = 0; i < 4; ++i){
    #pragma unroll
    for (int r = 0; r < 4; ++r){
      float bv = -__builtin_inff(); int bi = 0x7FFFFFFF;
      #pragma unroll
      for (int j = 0; j < 4; ++j){
        int col = n0 + wn * 64 + j * 16 + (lane & 15);
        if (col < NCLS){
          float v = acc[i][j][r] + bc[col];
          if (v > bv){ bv = v; bi = col; }
        }
      }
      for (int s = 1; s < 16; s <<= 1){
        float ov = __shfl_xor(bv, s);
        int   oi = __shfl_xor(bi, s);
        if (ov > bv || (ov == bv && oi < bi)){ bv = ov; bi = oi; }
      }
      if ((lane & 15) == 0){
        int rloc = wm * 64 + i * 16 + g * 4 + r;
        cmax[rloc * 4 + wn] = bv;
        cidx[rloc * 4 + wn] = bi;
      }
    }
  }
  __syncthreads();
  if (tid < 128){
    float bv = cmax[tid * 4]; int bi = cidx[tid * 4];
    #pragma unroll
    for (int wq = 1; wq < 4; ++wq){
      float v = cmax[tid * 4 + wq]; int i1 = cidx[tid * 4 + wq];
      if (v > bv || (v == bv && i1 < bi)){ bv = v; bi = i1; }
    }
    size_t row = (size_t)(m0 + tid);
    g_pmax[(size_t)nt * NROW + row] = bv;
    g_pidx[(size_t)nt * NROW + row] = bi;
  }
}

// ---------------- K5: tail: split-K reduce + 512->256->127 MLP + best-combine -----
__global__ __launch_bounds__(256) void k_tail(
    const float* __restrict__ bo1, const float* __restrict__ wo2,
    const float* __restrict__ bo2, const float* __restrict__ wo3,
    const float* __restrict__ bo3, float* __restrict__ out)
{
  __shared__ float o1f[512];
  __shared__ float o2f[256];
  __shared__ int   bis[60];
  const int s = blockIdx.x;
  const int tid = threadIdx.x;
  if (tid < 60){
    size_t row = (size_t)s * 60 + tid;
    float bv = -__builtin_inff(); int bi = 0x7FFFFFFF;
    for (int qn = 0; qn < NTILE_N; ++qn){
      float v = g_pmax[(size_t)qn * NROW + row];
      int   i = g_pidx[(size_t)qn * NROW + row];
      if (v > bv || (v == bv && i < bi)){ bv = v; bi = i; }
    }
    bis[tid] = bi;
  }
  for (int j = tid; j < 512; j += 256){
    float a = bo1[j];
    for (int ks = 0; ks < O1_NZ; ++ks) a += g_part[((size_t)ks * NSAMP + s) * 512 + j];
    o1f[j] = fmaxf(a, 0.f);
  }
  __syncthreads();
  {
    float a = bo2[tid];
    const float* wr = wo2 + (size_t)tid * 512;
    for (int i = 0; i < 512; i += 4){
      float4 w4 = *(const float4*)(wr + i);
      a += o1f[i]*w4.x + o1f[i+1]*w4.y + o1f[i+2]*w4.z + o1f[i+3]*w4.w;
    }
    o2f[tid] = fmaxf(a, 0.f);
  }
  __syncthreads();
  if (tid < 127){
    float a = bo3[tid];
    const float* wr = wo3 + (size_t)tid * 256;
    for (int i = 0; i < 256; i += 4){
      float4 w4 = *(const float4*)(wr + i);
      a += o2f[i]*w4.x + o2f[i+1]*w4.y + o2f[i+2]*w4.z + o2f[i+3]*w4.w;
    }
    out[s * 128 + tid] = fmaxf(a, 0.f);
  }
  if (tid == 0){
    int m = bis[0];
    for (int i = 1; i < 60; ++i) m = min(m, bis[i]);
    out[s * 128 + 127] = (float)m;
  }
}

extern "C" void kernel_launch(void* const* d_in, const int* in_sizes, int n_in,
                              void* d_out, int out_size, void* d_ws, size_t ws_size,
                              hipStream_t stream)
{
  (void)d_ws; (void)ws_size; (void)in_sizes; (void)n_in; (void)out_size;
  const int*   x      = (const int*)  d_in[0];
  const float* suit_w = (const float*)d_in[1];
  const float* suit_b = (const float*)d_in[2];
  const float* rank_w = (const float*)d_in[3];
  const float* rank_b = (const float*)d_in[4];
  const float* bns_g  = (const float*)d_in[5];
  const float* bns_b  = (const float*)d_in[6];
  const float* bns_m  = (const float*)d_in[7];
  const float* bns_v  = (const float*)d_in[8];
  const float* bnr_g  = (const float*)d_in[9];
  const float* bnr_b  = (const float*)d_in[10];
  const float* bnr_m  = (const float*)d_in[11];
  const float* bnr_v  = (const float*)d_in[12];
  const float* w1     = (const float*)d_in[13];
  const float* b1     = (const float*)d_in[14];
  const float* w2     = (const float*)d_in[15];
  const float* b2     = (const float*)d_in[16];
  const float* wc     = (const float*)d_in[17];
  const float* bc     = (const float*)d_in[18];
  const float* wo1    = (const float*)d_in[19];
  const float* bo1    = (const float*)d_in[20];
  const float* wo2    = (const float*)d_in[21];
  const float* bo2    = (const float*)d_in[22];
  const float* wo3    = (const float*)d_in[23];
  const float* bo3    = (const float*)d_in[24];
  float* out = (float*)d_out;

  hipLaunchKernelGGL(k_prep, dim3(11520), dim3(256), 0, stream, wc, wo1);
  hipLaunchKernelGGL(k_features, dim3(5760), dim3(256), 0, stream, x,
                     suit_w, suit_b, rank_w, rank_b,
                     bns_g, bns_b, bns_m, bns_v, bnr_g, bnr_b, bnr_m, bnr_v,
                     w1, b1, w2, b2);
  hipLaunchKernelGGL(k_fused, dim3(NTILE_N * NTILE_M + 180), dim3(512), 0, stream, bc);
  hipLaunchKernelGGL(k_tail, dim3(NSAMP), dim3(256), 0, stream,
                     bo1, wo2, bo2, wo3, bo3, out);
}

// Round 21
// 930.091 us; speedup vs baseline: 2.2082x; 1.0078x over previous
//
#include <hip/hip_runtime.h>

#define NSAMP 384
#define NCOMBO 60
#define NROW 23040
#define KDIM 512
#define NCLS 7463
#define NCLSP 7680
#define NTILE_N 30
#define NTILE_M 180
#define O1_NZ 30
#define O1_KZ 512

typedef short s16x8 __attribute__((ext_vector_type(8)));
typedef short s16x4 __attribute__((ext_vector_type(4)));
typedef float f32x4 __attribute__((ext_vector_type(4)));

// ---- module-level scratch (fast-family layout; every byte rewritten per call) ----
__device__ unsigned short g_wc_hi[NCLSP * KDIM];
__device__ unsigned short g_wc_lo[NCLSP * KDIM];
__device__ unsigned short g_h_hi[NROW * KDIM];
__device__ unsigned short g_h_lo[NROW * KDIM];
__device__ unsigned short g_rawbf[NROW * 256];          // == [NSAMP][15360]
__device__ unsigned short g_wo1bf[512 * 15360];
__device__ float          g_pmax[NTILE_N * NROW];       // [nt][row]
__device__ int            g_pidx[NTILE_N * NROW];
__device__ float          g_part[O1_NZ * NSAMP * 512];

__device__ __forceinline__ float bf2f(unsigned short u){
  union { unsigned int i; float f; } v; v.i = ((unsigned int)u) << 16; return v.f;
}
__device__ __forceinline__ unsigned short f2bf(float f){
  union { float f; unsigned int i; } v; v.f = f;
  unsigned int u = v.i;
  unsigned int r = (u + 0x7FFFu + ((u >> 16) & 1u)) >> 16;
  return (unsigned short)r;
}
__device__ __forceinline__ void gload16(const void* g, void* l){
  __builtin_amdgcn_global_load_lds((const __attribute__((address_space(1))) void*)g,
                                   (__attribute__((address_space(3))) void*)l, 16, 0, 0);
}

// ---------------- K0: wc -> bf16 hi/lo (pad to 7680) AND wo1 -> bf16 --------------
__global__ __launch_bounds__(256) void k_prep(const float* __restrict__ wc,
                                              const float* __restrict__ wo1)
{
  int b = blockIdx.x;
  if (b < 3840){
    int idx = (b * 256 + threadIdx.x) * 4;
    float4 w = {0.f, 0.f, 0.f, 0.f};
    if (idx < NCLS * KDIM) w = *(const float4*)(wc + idx);
    s16x4 hi, lo;
    float wv[4] = {w.x, w.y, w.z, w.w};
    #pragma unroll
    for (int i = 0; i < 4; ++i){
      unsigned short h = f2bf(wv[i]);
      hi[i] = (short)h;
      lo[i] = (short)f2bf(wv[i] - bf2f(h));
    }
    *(s16x4*)(g_wc_hi + idx) = hi;
    *(s16x4*)(g_wc_lo + idx) = lo;
  } else {
    int idx = ((b - 3840) * 256 + threadIdx.x) * 4;   // covers 512*15360 exactly
    float4 w = *(const float4*)(wo1 + idx);
    s16x4 v;
    v[0] = (short)f2bf(w.x); v[1] = (short)f2bf(w.y);
    v[2] = (short)f2bf(w.z); v[3] = (short)f2bf(w.w);
    *(s16x4*)(g_wo1bf + idx) = v;
  }
}

// ---------------- K1: per-combo features -> h hi/lo + raw bf16 ----------------
__global__ __launch_bounds__(256) void k_features(
    const int* __restrict__ x,
    const float* __restrict__ suit_w, const float* __restrict__ suit_b,
    const float* __restrict__ rank_w, const float* __restrict__ rank_b,
    const float* __restrict__ bns_g, const float* __restrict__ bns_b,
    const float* __restrict__ bns_m, const float* __restrict__ bns_v,
    const float* __restrict__ bnr_g, const float* __restrict__ bnr_b,
    const float* __restrict__ bnr_m, const float* __restrict__ bnr_v,
    const float* __restrict__ w1, const float* __restrict__ b1,
    const float* __restrict__ w2, const float* __restrict__ b2)
{
  __shared__ float raw_s[4][256];
  __shared__ float h1_s[4][512];
  __shared__ float w1s[512];
  __shared__ float w2s[1024];
  __shared__ float b1s[32];
  __shared__ float b2s[32];
  const int tid  = threadIdx.x;
  const int lane = tid & 63;
  const int wv   = tid >> 6;
  const int combo = blockIdx.x * 4 + wv;
  const int s = combo / 60;
  const int k = combo % 60;
  const int hp = k / 10, bt = k % 10;
  const int HP0[6]  = {0,0,0,1,1,2}, HP1[6] = {1,2,3,2,3,3};
  const int BT0[10] = {4,4,4,4,4,4,5,5,5,6};
  const int BT1[10] = {5,5,5,6,6,7,6,6,7,7};
  const int BT2[10] = {6,7,8,7,8,8,7,8,8,8};
  int cards[5] = {HP0[hp], HP1[hp], BT0[bt], BT1[bt], BT2[bt]};
  const int* xp = x + s * 18;
  int rk[5], st[5];
  #pragma unroll
  for (int c = 0; c < 5; ++c){ rk[c] = xp[2*cards[c]]; st[c] = xp[2*cards[c] + 1]; }

  // cooperative weight preload (visible after the first __syncthreads below)
  w1s[tid]       = w1[tid];
  w1s[tid + 256] = w1[tid + 256];
  #pragma unroll
  for (int i = 0; i < 4; ++i) w2s[tid + i * 256] = w2[tid + i * 256];
  if (tid < 32){ b1s[tid] = b1[tid]; b2s[tid] = b2[tid]; }

  {
    s16x4 rv;
    #pragma unroll
    for (int i = 0; i < 4; ++i){
      int e = lane * 4 + i;
      int o = e >> 4, l = e & 15;
      float v;
      if (l < 11){
        float a = 0.f;
        #pragma unroll
        for (int c = 0; c < 5; ++c){
          int d = rk[c] - l;
          if (d >= 0 && d < 5) a += rank_w[o*25 + c*5 + d];
        }
        a += rank_b[o];
        float inv = bnr_g[o] / sqrtf(bnr_v[o] + 1e-5f);
        v = a * inv + (bnr_b[o] - bnr_m[o] * inv);
      } else {
        int j = l - 11;
        float a = suit_b[o];
        #pragma unroll
        for (int c = 0; c < 5; ++c) if (st[c] == j) a += suit_w[o*5 + c];
        float inv = bns_g[o] / sqrtf(bns_v[o] + 1e-5f);
        v = a * inv + (bns_b[o] - bns_m[o] * inv);
      }
      v = fmaxf(v, 0.f);
      raw_s[wv][e] = v;
      rv[i] = (short)f2bf(v);
    }
    *(s16x4*)(g_rawbf + (size_t)s * 15360 + k * 256 + lane * 4) = rv;
  }
  __syncthreads();
  #pragma unroll
  for (int i = 0; i < 8; ++i){
    int e = lane + 64 * i;
    int o = e >> 5, j = e & 31;
    float a = b1s[j];
    #pragma unroll
    for (int l = 0; l < 16; ++l) a += raw_s[wv][o*16 + l] * w1s[j*16 + l];
    h1_s[wv][e] = fmaxf(a, 0.f);
  }
  __syncthreads();
  {
    s16x8 hv, lv;
    #pragma unroll
    for (int i = 0; i < 8; ++i){
      int e = lane * 8 + i;
      int o = e >> 5, j = e & 31;
      float a = b2s[j];
      #pragma unroll
      for (int l = 0; l < 32; ++l) a += h1_s[wv][o*32 + l] * w2s[j*32 + l];
      a = fmaxf(a, 0.f);
      unsigned short h = f2bf(a);
      hv[i] = (short)h;
      lv[i] = (short)f2bf(a - bf2f(h));
    }
    *(s16x8*)(g_h_hi + (size_t)combo * 512 + lane * 8) = hv;
    *(s16x8*)(g_h_lo + (size_t)combo * 512 + lane * 8) = lv;
  }
}

// ---------------- K2: fused logits GEMM (blocks <5400) + o-head GEMM (>=5400) -----
// Logits part = R16/R19 byte-exact (measured 817us x3). o1 part: 180 blocks
// appended, each = two 4-wave teams, one FULL 512-K z-slice each (16 BK=32
// steps) -- fixes R20's half-K bug (O1_KZ was 256 with only 30 z-slices).
__global__ __launch_bounds__(512, 4) void k_fused(const float* __restrict__ bc)
{
  __shared__ unsigned char lds[49152];
  const int tid  = threadIdx.x;
  const int blk  = blockIdx.x;

  if (blk >= NTILE_N * NTILE_M){
    // ---------------- o-head branch ----------------
    const int idx  = blk - NTILE_N * NTILE_M;   // 0..179
    const int nb   = idx & 3;                   // 4 n-tiles
    const int mb   = (idx >> 2) % 3;            // 3 m-tiles
    const int zp   = idx / 12;                  // 0..14
    const int team = tid >> 8;                  // 0/1
    const int ttid = tid & 255;
    const int z    = zp * 2 + team;             // 0..29
    const int lane = ttid & 63;
    const int twv  = ttid >> 6;                 // 0..3
    const int wr   = twv >> 1, wq = twv & 1;
    const int n0   = nb * 128;
    const int m0   = mb * 128;
    const int kc0  = z * O1_KZ;                 // full 512-K chunk per team
    unsigned char* As = lds + team * 16384;
    unsigned char* Bs = As + 8192;

    f32x4 acc[4][4];
    #pragma unroll
    for (int i = 0; i < 4; ++i)
      #pragma unroll
      for (int j = 0; j < 4; ++j)
        acc[i][j] = (f32x4){0.f, 0.f, 0.f, 0.f};

    const int rA = lane >> 2;                   // 0..15
    const int c0 = lane & 3;
    for (int kk = 0; kk < O1_KZ; kk += 32){
      int kc = kc0 + kk;
      __syncthreads();
      #pragma unroll
      for (int it = 0; it < 2; ++it){
        int seg = twv * 2 + it;                 // 0..7 (wave-uniform)
        int r   = seg * 16 + rA;                // 0..127
        int cs  = c0 ^ ((rA >> 1) & 3);         // pre-swizzled source chunk
        unsigned lb = (unsigned)(seg * 1024);
        gload16(g_rawbf + (size_t)(m0 + r) * 15360 + kc + cs * 8, As + lb);
        gload16(g_wo1bf + (size_t)(n0 + r) * 15360 + kc + cs * 8, Bs + lb);
      }
      __syncthreads();
      const int q = lane >> 4;
      s16x8 a[4];
      #pragma unroll
      for (int i = 0; i < 4; ++i){
        int row = wr * 64 + i * 16 + (lane & 15);
        a[i] = *(const s16x8*)(As + row * 64 + ((q ^ ((row >> 1) & 3)) * 16));
      }
      #pragma unroll
      for (int j = 0; j < 4; ++j){
        int col = wq * 64 + j * 16 + (lane & 15);
        s16x8 b = *(const s16x8*)(Bs + col * 64 + ((q ^ ((col >> 1) & 3)) * 16));
        #pragma unroll
        for (int i = 0; i < 4; ++i)
          acc[i][j] = __builtin_amdgcn_mfma_f32_16x16x32_bf16(a[i], b, acc[i][j], 0, 0, 0);
      }
    }
    const int g = lane >> 4;
    #pragma unroll
    for (int i = 0; i < 4; ++i)
      #pragma unroll
      for (int j = 0; j < 4; ++j)
        #pragma unroll
        for (int r = 0; r < 4; ++r){
          int gm = m0 + wr * 64 + i * 16 + g * 4 + r;
          int gn = n0 + wq * 64 + j * 16 + (lane & 15);
          g_part[((size_t)z * NSAMP + gm) * 512 + gn] = acc[i][j][r];
        }
    return;
  }

  // ---------------- logits branch (byte-exact R16) ----------------
  const int lane = tid & 63;
  const int wv   = tid >> 6;                 // 0..7
  const int wm   = wv >> 2, wn = wv & 3;     // 2M x 4N
  const int nt   = blk / NTILE_M;
  const int mt   = blk % NTILE_M;
  const int m0 = mt * 128;
  const int n0 = nt * 256;

  f32x4 acc[4][4];
  #pragma unroll
  for (int i = 0; i < 4; ++i)
    #pragma unroll
    for (int j = 0; j < 4; ++j)
      acc[i][j] = (f32x4){0.f, 0.f, 0.f, 0.f};

  const int rS = wv * 16 + (lane >> 2);              // 0..127
  const int cS = (lane & 3) ^ ((lane >> 3) & 3);     // pre-swizzled source chunk
  auto stage = [&](int buf, int t){
    const int p = t / 3, seg = t - p * 3;
    const int kc = p * 32;
    const unsigned short* As = (seg < 2) ? g_h_hi : g_h_lo;
    const unsigned short* Bs = (seg == 1) ? g_wc_lo : g_wc_hi;
    const unsigned base = buf * 24576 + wv * 1024;
    gload16(As + (size_t)(m0 + rS) * KDIM + kc + cS * 8, lds + base);
    gload16(Bs + (size_t)(n0 + rS) * KDIM + kc + cS * 8, lds + base + 8192);
    gload16(Bs + (size_t)(n0 + 128 + rS) * KDIM + kc + cS * 8, lds + base + 16384);
  };

  stage(0, 0);
  stage(1, 1);
  asm volatile("s_waitcnt vmcnt(3)" ::: "memory");   // tile0's 3 loads done
  __builtin_amdgcn_sched_barrier(0);
  __builtin_amdgcn_s_barrier();
  asm volatile("" ::: "memory");

  const int q = lane >> 4;                   // 16B k-chunk 0..3
  #pragma unroll 1
  for (int t = 0; t < 48; ++t){
    const unsigned cb = (unsigned)(t & 1) * 24576;
    s16x8 af[4], bf[4];
    #pragma unroll
    for (int i = 0; i < 4; ++i){
      int row = wm * 64 + i * 16 + (lane & 15);
      af[i] = *(const s16x8*)(lds + cb + row * 64 + ((q ^ ((row >> 1) & 3)) << 4));
    }
    #pragma unroll
    for (int j = 0; j < 4; ++j){
      int row = wn * 64 + j * 16 + (lane & 15);
      bf[j] = *(const s16x8*)(lds + cb + 8192 + row * 64 + ((q ^ ((row >> 1) & 3)) << 4));
    }
    __builtin_amdgcn_s_setprio(1);
    #pragma unroll
    for (int i = 0; i < 4; ++i)
      #pragma unroll
      for (int j = 0; j < 4; ++j)
        acc[i][j] = __builtin_amdgcn_mfma_f32_16x16x32_bf16(af[i], bf[j], acc[i][j], 0, 0, 0);
    __builtin_amdgcn_s_setprio(0);
    __builtin_amdgcn_sched_barrier(0);
    __builtin_amdgcn_s_barrier();            // all waves done reading buffer cb
    asm volatile("" ::: "memory");
    if (t + 2 < 48){
      stage(t & 1, t + 2);                   // overwrite cb; loads fly across barriers
      asm volatile("s_waitcnt vmcnt(3)" ::: "memory");  // tile t+1 confirmed
    } else {
      asm volatile("s_waitcnt vmcnt(0)" ::: "memory");  // tail drain
    }
    __builtin_amdgcn_sched_barrier(0);
    __builtin_amdgcn_s_barrier();
    asm volatile("" ::: "memory");
  }

  // epilogue: + bc, per-row argmax over this 256-col tile (ties -> lowest index)
  float* cmax = (float*)lds;                 // [128 rows][4 wn]
  int*   cidx = (int*)(lds + 2048);
  const int g = lane >> 4;
  #pragma unroll
  for (int i = 0; i < 4; ++i){
    #pragma unroll
    for (int r = 0; r < 4; ++r){
      float bv = -__builtin_inff(); int bi = 0x7FFFFFFF;
      #pragma unroll
      for (int j = 0; j < 4; ++j){
        int col = n0 + wn * 64 + j * 16 + (lane & 15);
        if (col < NCLS){
          float v = acc[i][j][r] + bc[col];
          if (v > bv){ bv = v; bi = col; }
        }
      }
      for (int s = 1; s < 16; s <<= 1){
        float ov = __shfl_xor(bv, s);
        int   oi = __shfl_xor(bi, s);
        if (ov > bv || (ov == bv && oi < bi)){ bv = ov; bi = oi; }
      }
      if ((lane & 15) == 0){
        int rloc = wm * 64 + i * 16 + g * 4 + r;
        cmax[rloc * 4 + wn] = bv;
        cidx[rloc * 4 + wn] = bi;
      }
    }
  }
  __syncthreads();
  if (tid < 128){
    float bv = cmax[tid * 4]; int bi = cidx[tid * 4];
    #pragma unroll
    for (int wq = 1; wq < 4; ++wq){
      float v = cmax[tid * 4 + wq]; int i1 = cidx[tid * 4 + wq];
      if (v > bv || (v == bv && i1 < bi)){ bv = v; bi = i1; }
    }
    size_t row = (size_t)(m0 + tid);
    g_pmax[(size_t)nt * NROW + row] = bv;
    g_pidx[(size_t)nt * NROW + row] = bi;
  }
}

// ---------------- K5: tail: split-K reduce + 512->256->127 MLP + best-combine -----
__global__ __launch_bounds__(256) void k_tail(
    const float* __restrict__ bo1, const float* __restrict__ wo2,
    const float* __restrict__ bo2, const float* __restrict__ wo3,
    const float* __restrict__ bo3, float* __restrict__ out)
{
  __shared__ float o1f[512];
  __shared__ float o2f[256];
  __shared__ int   bis[60];
  const int s = blockIdx.x;
  const int tid = threadIdx.x;
  if (tid < 60){
    size_t row = (size_t)s * 60 + tid;
    float bv = -__builtin_inff(); int bi = 0x7FFFFFFF;
    for (int qn = 0; qn < NTILE_N; ++qn){
      float v = g_pmax[(size_t)qn * NROW + row];
      int   i = g_pidx[(size_t)qn * NROW + row];
      if (v > bv || (v == bv && i < bi)){ bv = v; bi = i; }
    }
    bis[tid] = bi;
  }
  for (int j = tid; j < 512; j += 256){
    float a = bo1[j];
    for (int ks = 0; ks < O1_NZ; ++ks) a += g_part[((size_t)ks * NSAMP + s) * 512 + j];
    o1f[j] = fmaxf(a, 0.f);
  }
  __syncthreads();
  {
    float a = bo2[tid];
    const float* wr = wo2 + (size_t)tid * 512;
    for (int i = 0; i < 512; i += 4){
      float4 w4 = *(const float4*)(wr + i);
      a += o1f[i]*w4.x + o1f[i+1]*w4.y + o1f[i+2]*w4.z + o1f[i+3]*w4.w;
    }
    o2f[tid] = fmaxf(a, 0.f);
  }
  __syncthreads();
  if (tid < 127){
    float a = bo3[tid];
    const float* wr = wo3 + (size_t)tid * 256;
    for (int i = 0; i < 256; i += 4){
      float4 w4 = *(const float4*)(wr + i);
      a += o2f[i]*w4.x + o2f[i+1]*w4.y + o2f[i+2]*w4.z + o2f[i+3]*w4.w;
    }
    out[s * 128 + tid] = fmaxf(a, 0.f);
  }
  if (tid == 0){
    int m = bis[0];
    for (int i = 1; i < 60; ++i) m = min(m, bis[i]);
    out[s * 128 + 127] = (float)m;
  }
}

extern "C" void kernel_launch(void* const* d_in, const int* in_sizes, int n_in,
                              void* d_out, int out_size, void* d_ws, size_t ws_size,
                              hipStream_t stream)
{
  (void)d_ws; (void)ws_size; (void)in_sizes; (void)n_in; (void)out_size;
  const int*   x      = (const int*)  d_in[0];
  const float* suit_w = (const float*)d_in[1];
  const float* suit_b = (const float*)d_in[2];
  const float* rank_w = (const float*)d_in[3];
  const float* rank_b = (const float*)d_in[4];
  const float* bns_g  = (const float*)d_in[5];
  const float* bns_b  = (const float*)d_in[6];
  const float* bns_m  = (const float*)d_in[7];
  const float* bns_v  = (const float*)d_in[8];
  const float* bnr_g  = (const float*)d_in[9];
  const float* bnr_b  = (const float*)d_in[10];
  const float* bnr_m  = (const float*)d_in[11];
  const float* bnr_v  = (const float*)d_in[12];
  const float* w1     = (const float*)d_in[13];
  const float* b1     = (const float*)d_in[14];
  const float* w2     = (const float*)d_in[15];
  const float* b2     = (const float*)d_in[16];
  const float* wc     = (const float*)d_in[17];
  const float* bc     = (const float*)d_in[18];
  const float* wo1    = (const float*)d_in[19];
  const float* bo1    = (const float*)d_in[20];
  const float* wo2    = (const float*)d_in[21];
  const float* bo2    = (const float*)d_in[22];
  const float* wo3    = (const float*)d_in[23];
  const float* bo3    = (const float*)d_in[24];
  float* out = (float*)d_out;

  hipLaunchKernelGGL(k_prep, dim3(11520), dim3(256), 0, stream, wc, wo1);
  hipLaunchKernelGGL(k_features, dim3(5760), dim3(256), 0, stream, x,
                     suit_w, suit_b, rank_w, rank_b,
                     bns_g, bns_b, bns_m, bns_v, bnr_g, bnr_b, bnr_m, bnr_v,
                     w1, b1, w2, b2);
  hipLaunchKernelGGL(k_fused, dim3(NTILE_N * NTILE_M + 180), dim3(512), 0, stream, bc);
  hipLaunchKernelGGL(k_tail, dim3(NSAMP), dim3(256), 0, stream,
                     bo1, wo2, bo2, wo3, bo3, out);
}